// Round 1
// baseline (317.598 us; speedup 1.0000x reference)
//
#include <hip/hip_runtime.h>
#include <math.h>

#define B_  8
#define R_  64
#define C_  256
#define NH_ 8
#define N_  4096
#define HD_ 32

__device__ __forceinline__ float softplus_rcp(float s) {
    return 1.f / __logf(1.f + __expf(s));     // 1/softplus, fast intrinsics
}

// ---------------------------------------------------------------------------
// Kernel NB: fused (kernelN + kernelB2).
// Token-major: each block owns 64 consecutive tokens (always within one batch
// since 4096 % 64 == 0) across the FULL channel dim C=256, so the full-C
// norm-rescale scalars (qs, ks) are computed in-kernel with a wave butterfly
// and k+pos is read from HBM exactly once (kernelN's separate k+pos pass and
// the ks_arr roundtrip are gone).
// Per 32-token tile:
//   phase 1 (wave-parallel, lane owns 4 channels): load q,k,pos,v; compute
//     qs -> global, kfin = kv^3*ks -> LDS, v -> LDS, ksum partials in regs.
//   phase 2: thread (h = t>>5, cg = t&7, dg = (t&31)>>3) accumulates a 4x8
//     outer-product sub-tile of this head's 32x32 kv (32B LDS per 32 FMA,
//     2.5x less LDS traffic per FMA than old B2's 1x4 step).
// Epilogue: atomicAdd kv + ksum partials (64 partial blocks per batch).
// ---------------------------------------------------------------------------
__global__ __launch_bounds__(256) void kernelNB(
        const float* __restrict__ qkv, const float* __restrict__ pos,
        const float* __restrict__ scale,
        float* __restrict__ qs_arr, float* __restrict__ kv_ws,
        float* __restrict__ ksum_ws) {
    __shared__ float kf_s[32 * C_];      // 32 KB
    __shared__ float v_s [32 * C_];      // 32 KB
    __shared__ float rsc_s[C_];          // 1 KB
    __shared__ float kred_s[4 * C_];     // 4 KB   (ksum cross-wave reduce)

    const int t    = threadIdx.x;
    const int wave = t >> 6, lane = t & 63;
    const int c0   = lane * 4;
    const int tok0 = blockIdx.x * 64;
    const int b    = tok0 >> 12;         // tok0 / N_

    if (t < C_) rsc_s[t] = softplus_rcp(scale[t]);
    __syncthreads();

    const size_t qbase = (size_t)tok0 * C_;
    const size_t kbase = (size_t)B_ * N_ * C_ + qbase;
    const size_t vbase = (size_t)2 * B_ * N_ * C_ + qbase;

    const int h  = t >> 5;
    const int l  = t & 31;
    const int cg = l & 7;                // c sub-tile: channels cg*4 .. cg*4+3
    const int dg = l >> 3;               // d sub-tile: channels dg*8 .. dg*8+7

    const float rs0 = rsc_s[c0 + 0], rs1 = rsc_s[c0 + 1];
    const float rs2 = rsc_s[c0 + 2], rs3 = rsc_s[c0 + 3];

    float acc[4][8];
    #pragma unroll
    for (int ii = 0; ii < 4; ii++)
        #pragma unroll
        for (int jj = 0; jj < 8; jj++) acc[ii][jj] = 0.f;
    float ksp[4] = {0.f, 0.f, 0.f, 0.f};

    for (int tile = 0; tile < 2; tile++) {
        const int nb0 = tile * 32;
        // ---- phase 1: stage + per-token scalars (wave w owns rows w*8..w*8+7)
        #pragma unroll
        for (int i = 0; i < 8; i++) {
            const int row = wave * 8 + i;            // 0..31 within tile
            const int tok = tok0 + nb0 + row;
            const int n   = tok & (N_ - 1);
            const size_t off = (size_t)(nb0 + row) * C_ + c0;
            const float4 q4 = *(const float4*)(qkv + qbase + off);
            const float4 k4 = *(const float4*)(qkv + kbase + off);
            const float4 v4 = *(const float4*)(qkv + vbase + off);
            const float4 p4 = *(const float4*)(pos + (size_t)n * C_ + c0);

            const float qv0 = (fmaxf(q4.x, 0.f) + 1e-6f) * rs0;
            const float qv1 = (fmaxf(q4.y, 0.f) + 1e-6f) * rs1;
            const float qv2 = (fmaxf(q4.z, 0.f) + 1e-6f) * rs2;
            const float qv3 = (fmaxf(q4.w, 0.f) + 1e-6f) * rs3;
            const float kw0 = (fmaxf(k4.x + p4.x, 0.f) + 1e-6f) * rs0;
            const float kw1 = (fmaxf(k4.y + p4.y, 0.f) + 1e-6f) * rs1;
            const float kw2 = (fmaxf(k4.z + p4.z, 0.f) + 1e-6f) * rs2;
            const float kw3 = (fmaxf(k4.w + p4.w, 0.f) + 1e-6f) * rs3;

            const float q30 = qv0 * qv0 * qv0, q31 = qv1 * qv1 * qv1;
            const float q32 = qv2 * qv2 * qv2, q33 = qv3 * qv3 * qv3;
            const float k30 = kw0 * kw0 * kw0, k31 = kw1 * kw1 * kw1;
            const float k32 = kw2 * kw2 * kw2, k33 = kw3 * kw3 * kw3;

            float sq2 = qv0 * qv0 + qv1 * qv1 + qv2 * qv2 + qv3 * qv3;
            float sq6 = q30 * q30 + q31 * q31 + q32 * q32 + q33 * q33;
            float sk2 = kw0 * kw0 + kw1 * kw1 + kw2 * kw2 + kw3 * kw3;
            float sk6 = k30 * k30 + k31 * k31 + k32 * k32 + k33 * k33;
            #pragma unroll
            for (int m = 1; m < 64; m <<= 1) {
                sq2 += __shfl_xor(sq2, m, 64);
                sq6 += __shfl_xor(sq6, m, 64);
                sk2 += __shfl_xor(sk2, m, 64);
                sk6 += __shfl_xor(sk6, m, 64);
            }
            if (lane == 0) qs_arr[tok] = sqrtf(sq2) * rsqrtf(sq6);
            const float ks = sqrtf(sk2) * rsqrtf(sk6);

            float4 kf;
            kf.x = k30 * ks;  kf.y = k31 * ks;
            kf.z = k32 * ks;  kf.w = k33 * ks;
            *(float4*)&kf_s[row * C_ + c0] = kf;
            *(float4*)&v_s [row * C_ + c0] = v4;
            ksp[0] += kf.x;  ksp[1] += kf.y;
            ksp[2] += kf.z;  ksp[3] += kf.w;
        }
        __syncthreads();
        // ---- phase 2: kv 4x8 outer-product accumulation from LDS ----
        {
            const float* kfp = kf_s + h * HD_ + cg * 4;
            const float* vp  = v_s  + h * HD_ + dg * 8;
            #pragma unroll 8
            for (int nl = 0; nl < 32; nl++) {
                const float4 kr = *(const float4*)(kfp + nl * C_);
                const float4 va = *(const float4*)(vp  + nl * C_);
                const float4 vb = *(const float4*)(vp  + nl * C_ + 4);
                const float kk[4] = {kr.x, kr.y, kr.z, kr.w};
                const float vv[8] = {va.x, va.y, va.z, va.w,
                                     vb.x, vb.y, vb.z, vb.w};
                #pragma unroll
                for (int ii = 0; ii < 4; ii++)
                    #pragma unroll
                    for (int jj = 0; jj < 8; jj++)
                        acc[ii][jj] = fmaf(kk[ii], vv[jj], acc[ii][jj]);
            }
        }
        __syncthreads();
    }

    // ---- epilogue: kv partials (unique per thread within block) ----
    float* kvdst = kv_ws + (size_t)(b * NH_ + h) * 1024 + (cg * 4) * HD_ + dg * 8;
    #pragma unroll
    for (int ii = 0; ii < 4; ii++)
        #pragma unroll
        for (int jj = 0; jj < 8; jj++)
            atomicAdd(kvdst + ii * HD_ + jj, acc[ii][jj]);

    // ---- ksum: cross-wave reduce then one atomic per channel ----
    *(float4*)&kred_s[wave * C_ + c0] = make_float4(ksp[0], ksp[1], ksp[2], ksp[3]);
    __syncthreads();
    if (t < C_) {
        const float s = kred_s[t] + kred_s[C_ + t] + kred_s[2 * C_ + t]
                      + kred_s[3 * C_ + t];
        atomicAdd(&ksum_ws[b * C_ + t], s);   // bh*32+c == b*256 + t
    }
}

// ---------------------------------------------------------------------------
// Kernel CD2: fused attention epilogue + both depthwise convs; out written
// ONCE via plain float4 stores (each lane covers a full 128B line across its
// 8 stores -> L2 write-combines to full-line HBM writes; nontemporal here
// caused 4x write amplification in R4).  [unchanged from verified version]
// ---------------------------------------------------------------------------
__global__ __launch_bounds__(256) void kernelCD2(
        const float* __restrict__ qkv, const float* __restrict__ qs_arr,
        const float* __restrict__ kv_ws, const float* __restrict__ ksum_ws,
        const float* __restrict__ scale,
        const float* __restrict__ w_v,  const float* __restrict__ b_v,
        const float* __restrict__ w_dwc, const float* __restrict__ b_dwc,
        float* __restrict__ out) {
    __shared__ float v_s[20 * 20 * 32];   // 51.2 KB; reused as conv_s (256*33)
    __shared__ float kv_s[1024];
    __shared__ float ks_s[32];
    __shared__ float rsc_s[32];
    const int t    = threadIdx.x;
    const int tile = blockIdx.x;
    const int h    = blockIdx.y;
    const int b    = blockIdx.z;
    const int ty0  = (tile >> 2) * 16, tx0 = (tile & 3) * 16;
    const int bh   = b * NH_ + h;

    ((float4*)kv_s)[t] = ((const float4*)(kv_ws + (size_t)bh * 1024))[t];
    if (t < 32) {
        ks_s[t]  = ksum_ws[bh * HD_ + t];
        rsc_s[t] = softplus_rcp(scale[h * HD_ + t]);
    }

    const float* vb = qkv + (size_t)2 * B_ * N_ * C_ + (size_t)b * N_ * C_ + h * HD_;
    #pragma unroll
    for (int i = 0; i < 13; i++) {
        const int idx = i * 256 + t;
        if (idx < 3200) {
            const int pix = idx >> 3, d4 = (idx & 7) * 4;
            const int yy = pix / 20, xx = pix - yy * 20;
            const int gy = ty0 + yy - 2, gx = tx0 + xx - 2;
            float4 val = make_float4(0.f, 0.f, 0.f, 0.f);
            if (gy >= 0 && gy < R_ && gx >= 0 && gx < R_)
                val = *(const float4*)(vb + (size_t)(gy * R_ + gx) * C_ + d4);
            *(float4*)&v_s[pix * 32 + d4] = val;
        }
    }

    const int c  = t & 31, pg = t >> 5;
    float wv[9], wd[25];
    {
        const float* wvp = w_v + (size_t)(h * HD_ + c) * 9;
        const float* wdp = w_dwc + (size_t)c * 25;
        #pragma unroll
        for (int i = 0; i < 9; i++)  wv[i] = wvp[i];
        #pragma unroll
        for (int i = 0; i < 25; i++) wd[i] = wdp[i];
    }
    const float bias = b_v[h * HD_ + c] + b_dwc[c];
    __syncthreads();

    // ---- conv phase: thread = (channel c, 2 tile rows), ring window ----
    float res[32];
    #pragma unroll
    for (int r2 = 0; r2 < 2; r2++) {
        const int ty = pg * 2 + r2;
        float win[5][5];
        #pragma unroll
        for (int j = 0; j < 5; j++)
            #pragma unroll
            for (int i = 0; i < 5; i++)
                win[j][i] = v_s[((ty + i) * 20 + j) * 32 + c];
        #pragma unroll
        for (int tx = 0; tx < 16; tx++) {
            float a = bias;
            #pragma unroll
            for (int j = 0; j < 5; j++) {
                const int slot = (tx + j) % 5;
                #pragma unroll
                for (int i = 0; i < 5; i++)
                    a = fmaf(wd[i * 5 + j], win[slot][i], a);
            }
            #pragma unroll
            for (int j = 1; j < 4; j++) {
                const int slot = (tx + j) % 5;
                #pragma unroll
                for (int i = 1; i < 4; i++)
                    a = fmaf(wv[(i - 1) * 3 + (j - 1)], win[slot][i], a);
            }
            res[r2 * 16 + tx] = a;
            if (tx < 15) {
                const int slot = tx % 5;
                #pragma unroll
                for (int i = 0; i < 5; i++)
                    win[slot][i] = v_s[((ty + i) * 20 + (tx + 5)) * 32 + c];
            }
        }
    }
    __syncthreads();
    #pragma unroll
    for (int r2 = 0; r2 < 2; r2++)
        #pragma unroll
        for (int tx = 0; tx < 16; tx++)
            v_s[((pg * 2 + r2) * 16 + tx) * 33 + c] = res[r2 * 16 + tx];
    __syncthreads();

    // ---- attention phase: thread = pixel; q-feature recomputed on the fly ----
    {
        const int tyy = t >> 4, txx = t & 15;
        const int n   = (ty0 + tyy) * R_ + (tx0 + txx);
        const int tok = b * N_ + n;
        float q[32];
        const float4* qsrc = (const float4*)(qkv + (size_t)tok * C_ + h * HD_);
        #pragma unroll
        for (int i = 0; i < 8; i++) ((float4*)q)[i] = qsrc[i];
        const float qs = qs_arr[tok];
        #pragma unroll
        for (int i = 0; i < 32; i++) {
            const float r = (fmaxf(q[i], 0.f) + 1e-6f) * rsc_s[i];
            q[i] = r * r * r * qs;
        }

        float denom = 1e-6f;
        #pragma unroll
        for (int cc = 0; cc < 32; cc++) denom = fmaf(q[cc], ks_s[cc], denom);
        const float z = 1.f / denom;

        float o[32];
        #pragma unroll
        for (int i = 0; i < 32; i++) o[i] = 0.f;
        #pragma unroll
        for (int cc = 0; cc < 32; cc++) {
            const float qc = q[cc];
            #pragma unroll
            for (int d = 0; d < 32; d++)
                o[d] = fmaf(qc, kv_s[cc * 32 + d], o[d]);
        }
        float4* dst = (float4*)(out + (size_t)tok * C_ + h * HD_);
        #pragma unroll
        for (int i = 0; i < 8; i++) {
            float4 v4;
            v4.x = fmaf(o[i*4+0], z, v_s[t * 33 + i*4+0]);
            v4.y = fmaf(o[i*4+1], z, v_s[t * 33 + i*4+1]);
            v4.z = fmaf(o[i*4+2], z, v_s[t * 33 + i*4+2]);
            v4.w = fmaf(o[i*4+3], z, v_s[t * 33 + i*4+3]);
            dst[i] = v4;
        }
    }
}

// ---------------------------------------------------------------------------
extern "C" void kernel_launch(void* const* d_in, const int* in_sizes, int n_in,
                              void* d_out, int out_size, void* d_ws, size_t ws_size,
                              hipStream_t stream) {
    const float* qkv   = (const float*)d_in[0];
    const float* pos   = (const float*)d_in[1];
    const float* scale = (const float*)d_in[2];
    const float* w_v   = (const float*)d_in[3];
    const float* b_v   = (const float*)d_in[4];
    const float* w_dwc = (const float*)d_in[5];
    const float* b_dwc = (const float*)d_in[6];
    float* out = (float*)d_out;

    float* qs_arr  = (float*)d_ws;                   // B*N floats
    float* kv_ws   = qs_arr + (size_t)B_ * N_;       // 64*1024 floats
    float* ksum_ws = kv_ws + 64 * 1024;              // 64*32 floats

    (void)hipMemsetAsync(kv_ws, 0, (64 * 1024 + 64 * 32) * sizeof(float), stream);
    kernelNB<<<dim3(512), 256, 0, stream>>>(qkv, pos, scale, qs_arr, kv_ws, ksum_ws);
    kernelCD2<<<dim3(16, NH_, B_), 256, 0, stream>>>(qkv, qs_arr, kv_ws, ksum_ws,
                                                     scale, w_v, b_v, w_dwc, b_dwc, out);
}

// Round 2
// 230.567 us; speedup vs baseline: 1.3775x; 1.3775x over previous
//
#include <hip/hip_runtime.h>
#include <math.h>

#define B_  8
#define R_  64
#define C_  256
#define NH_ 8
#define N_  4096
#define HD_ 32

__device__ __forceinline__ float softplus_rcp(float s) {
    return 1.f / __logf(1.f + __expf(s));     // 1/softplus, fast intrinsics
}

// ---------------------------------------------------------------------------
// Kernel NB2: fused norms + kv aggregation, NO ATOMICS.
// R1 lesson: 4.19M contended device-scope atomicAdds -> 131.7 MB of
// memory-side RMW traffic (32B each) and full serialization (VALUBusy 7.5%).
// Here each block writes its private 32x32x8-head kv partial (8192 floats,
// LDS-staged then float4-coalesced) + 256-ch ksum partial; kernelR reduces.
// Occupancy: 37 KB LDS, 1024 blocks -> 4 blocks/CU on all 256 CUs.
// Each block owns 32 consecutive tokens (one batch), 2 tiles of 16 rows:
//   phase 1: lane owns 4 channels of full C=256; load q,k,pos,v; wave
//     butterfly for full-C norms; qs -> global, kfin=kv^3*ks -> LDS, v -> LDS.
//   phase 2: thread (h=t>>5, cg, dg) accumulates 4x8 sub-tile of head kv.
// ---------------------------------------------------------------------------
__global__ __launch_bounds__(256) void kernelNB2(
        const float* __restrict__ qkv, const float* __restrict__ pos,
        const float* __restrict__ scale,
        float* __restrict__ qs_arr, float* __restrict__ part,
        float* __restrict__ kspart) {
    __shared__ float smem[9472];            // 37 KB
    float* kf_s   = smem;                   // [16][256] (epilogue: stage[8192])
    float* v_s    = smem + 4096;            // [16][256]
    float* rsc_s  = smem + 8192;            // [256]
    float* kred_s = smem + 8448;            // [4][256]

    const int t    = threadIdx.x;
    const int wave = t >> 6, lane = t & 63;
    const int c0   = lane * 4;
    const int blk  = blockIdx.x;
    const int tok0 = blk * 32;

    if (t < C_) rsc_s[t] = softplus_rcp(scale[t]);
    __syncthreads();

    const size_t qbase = (size_t)tok0 * C_;
    const size_t kbase = (size_t)B_ * N_ * C_ + qbase;
    const size_t vbase = (size_t)2 * B_ * N_ * C_ + qbase;

    const int h  = t >> 5;
    const int l  = t & 31;
    const int cg = l & 7;                   // c sub-tile: cg*4 .. cg*4+3
    const int dg = l >> 3;                  // d sub-tile: dg*8 .. dg*8+7

    const float rs0 = rsc_s[c0 + 0], rs1 = rsc_s[c0 + 1];
    const float rs2 = rsc_s[c0 + 2], rs3 = rsc_s[c0 + 3];

    float acc[4][8];
    #pragma unroll
    for (int ii = 0; ii < 4; ii++)
        #pragma unroll
        for (int jj = 0; jj < 8; jj++) acc[ii][jj] = 0.f;
    float ksp[4] = {0.f, 0.f, 0.f, 0.f};

    for (int tile = 0; tile < 2; tile++) {
        const int nb0 = tile * 16;
        // ---- phase 1: stage + per-token scalars (wave owns rows wave*4..+3)
        #pragma unroll
        for (int i = 0; i < 4; i++) {
            const int row = wave * 4 + i;            // 0..15 within tile
            const int tok = tok0 + nb0 + row;
            const int n   = tok & (N_ - 1);
            const size_t off = (size_t)(nb0 + row) * C_ + c0;
            const float4 q4 = *(const float4*)(qkv + qbase + off);
            const float4 k4 = *(const float4*)(qkv + kbase + off);
            const float4 v4 = *(const float4*)(qkv + vbase + off);
            const float4 p4 = *(const float4*)(pos + (size_t)n * C_ + c0);

            const float qv0 = (fmaxf(q4.x, 0.f) + 1e-6f) * rs0;
            const float qv1 = (fmaxf(q4.y, 0.f) + 1e-6f) * rs1;
            const float qv2 = (fmaxf(q4.z, 0.f) + 1e-6f) * rs2;
            const float qv3 = (fmaxf(q4.w, 0.f) + 1e-6f) * rs3;
            const float kw0 = (fmaxf(k4.x + p4.x, 0.f) + 1e-6f) * rs0;
            const float kw1 = (fmaxf(k4.y + p4.y, 0.f) + 1e-6f) * rs1;
            const float kw2 = (fmaxf(k4.z + p4.z, 0.f) + 1e-6f) * rs2;
            const float kw3 = (fmaxf(k4.w + p4.w, 0.f) + 1e-6f) * rs3;

            const float q30 = qv0 * qv0 * qv0, q31 = qv1 * qv1 * qv1;
            const float q32 = qv2 * qv2 * qv2, q33 = qv3 * qv3 * qv3;
            const float k30 = kw0 * kw0 * kw0, k31 = kw1 * kw1 * kw1;
            const float k32 = kw2 * kw2 * kw2, k33 = kw3 * kw3 * kw3;

            float sq2 = qv0 * qv0 + qv1 * qv1 + qv2 * qv2 + qv3 * qv3;
            float sq6 = q30 * q30 + q31 * q31 + q32 * q32 + q33 * q33;
            float sk2 = kw0 * kw0 + kw1 * kw1 + kw2 * kw2 + kw3 * kw3;
            float sk6 = k30 * k30 + k31 * k31 + k32 * k32 + k33 * k33;
            #pragma unroll
            for (int m = 1; m < 64; m <<= 1) {
                sq2 += __shfl_xor(sq2, m, 64);
                sq6 += __shfl_xor(sq6, m, 64);
                sk2 += __shfl_xor(sk2, m, 64);
                sk6 += __shfl_xor(sk6, m, 64);
            }
            if (lane == 0) qs_arr[tok] = sqrtf(sq2) * rsqrtf(sq6);
            const float ks = sqrtf(sk2) * rsqrtf(sk6);

            float4 kf;
            kf.x = k30 * ks;  kf.y = k31 * ks;
            kf.z = k32 * ks;  kf.w = k33 * ks;
            *(float4*)&kf_s[row * C_ + c0] = kf;
            *(float4*)&v_s [row * C_ + c0] = v4;
            ksp[0] += kf.x;  ksp[1] += kf.y;
            ksp[2] += kf.z;  ksp[3] += kf.w;
        }
        __syncthreads();
        // ---- phase 2: kv 4x8 outer-product accumulation from LDS ----
        {
            const float* kfp = kf_s + h * HD_ + cg * 4;
            const float* vp  = v_s  + h * HD_ + dg * 8;
            #pragma unroll 4
            for (int nl = 0; nl < 16; nl++) {
                const float4 kr = *(const float4*)(kfp + nl * C_);
                const float4 va = *(const float4*)(vp  + nl * C_);
                const float4 vb = *(const float4*)(vp  + nl * C_ + 4);
                const float kk[4] = {kr.x, kr.y, kr.z, kr.w};
                const float vv[8] = {va.x, va.y, va.z, va.w,
                                     vb.x, vb.y, vb.z, vb.w};
                #pragma unroll
                for (int ii = 0; ii < 4; ii++)
                    #pragma unroll
                    for (int jj = 0; jj < 8; jj++)
                        acc[ii][jj] = fmaf(kk[ii], vv[jj], acc[ii][jj]);
            }
        }
        __syncthreads();
    }

    // ---- epilogue: stage kv partial in LDS, write coalesced (no atomics) --
    #pragma unroll
    for (int ii = 0; ii < 4; ii++) {
        float4 a = make_float4(acc[ii][0], acc[ii][1], acc[ii][2], acc[ii][3]);
        float4 b = make_float4(acc[ii][4], acc[ii][5], acc[ii][6], acc[ii][7]);
        const int base = h * 1024 + (cg * 4 + ii) * 32 + dg * 8;
        *(float4*)&smem[base]     = a;
        *(float4*)&smem[base + 4] = b;
    }
    *(float4*)&kred_s[wave * 256 + c0] =
        make_float4(ksp[0], ksp[1], ksp[2], ksp[3]);
    __syncthreads();
    float* pdst = part + (size_t)blk * 8192;
    #pragma unroll
    for (int i = 0; i < 8; i++)
        *(float4*)&pdst[i * 1024 + t * 4] = *(const float4*)&smem[i * 1024 + t * 4];
    kspart[(size_t)blk * 256 + t] =
        kred_s[t] + kred_s[256 + t] + kred_s[512 + t] + kred_s[768 + t];
}

// ---------------------------------------------------------------------------
// Kernel R: reduce 128 per-block partials -> kv_ws[64][1024], ksum_ws[64][32].
// Grid 256 = 64 bh x 4 quarters; per-iteration loads are 1 KB contiguous.
// Writes kv_ws/ksum_ws destructively (no memset needed).
// ---------------------------------------------------------------------------
__global__ __launch_bounds__(256) void kernelR(
        const float* __restrict__ part, const float* __restrict__ kspart,
        float* __restrict__ kv_ws, float* __restrict__ ksum_ws) {
    const int t  = threadIdx.x;
    const int bh = blockIdx.x >> 2, q = blockIdx.x & 3;
    const int b  = bh >> 3, h = bh & 7;

    const float* p = part + (size_t)(b * 128) * 8192 + h * 1024 + q * 256 + t;
    float s = 0.f;
    #pragma unroll 4
    for (int j = 0; j < 128; j++) s += p[(size_t)j * 8192];
    kv_ws[bh * 1024 + q * 256 + t] = s;

    if (q == 0 && t < 32) {
        const float* kp = kspart + (size_t)(b * 128) * 256 + h * 32 + t;
        float s2 = 0.f;
        #pragma unroll 8
        for (int j = 0; j < 128; j++) s2 += kp[(size_t)j * 256];
        ksum_ws[bh * 32 + t] = s2;
    }
}

// ---------------------------------------------------------------------------
// Kernel CD2: fused attention epilogue + both depthwise convs; out written
// ONCE via plain float4 stores (each lane covers a full 128B line across its
// 8 stores -> L2 write-combines to full-line HBM writes; nontemporal here
// caused 4x write amplification in R4).  [unchanged from verified version]
// ---------------------------------------------------------------------------
__global__ __launch_bounds__(256) void kernelCD2(
        const float* __restrict__ qkv, const float* __restrict__ qs_arr,
        const float* __restrict__ kv_ws, const float* __restrict__ ksum_ws,
        const float* __restrict__ scale,
        const float* __restrict__ w_v,  const float* __restrict__ b_v,
        const float* __restrict__ w_dwc, const float* __restrict__ b_dwc,
        float* __restrict__ out) {
    __shared__ float v_s[20 * 20 * 32];   // 51.2 KB; reused as conv_s (256*33)
    __shared__ float kv_s[1024];
    __shared__ float ks_s[32];
    __shared__ float rsc_s[32];
    const int t    = threadIdx.x;
    const int tile = blockIdx.x;
    const int h    = blockIdx.y;
    const int b    = blockIdx.z;
    const int ty0  = (tile >> 2) * 16, tx0 = (tile & 3) * 16;
    const int bh   = b * NH_ + h;

    ((float4*)kv_s)[t] = ((const float4*)(kv_ws + (size_t)bh * 1024))[t];
    if (t < 32) {
        ks_s[t]  = ksum_ws[bh * HD_ + t];
        rsc_s[t] = softplus_rcp(scale[h * HD_ + t]);
    }

    const float* vb = qkv + (size_t)2 * B_ * N_ * C_ + (size_t)b * N_ * C_ + h * HD_;
    #pragma unroll
    for (int i = 0; i < 13; i++) {
        const int idx = i * 256 + t;
        if (idx < 3200) {
            const int pix = idx >> 3, d4 = (idx & 7) * 4;
            const int yy = pix / 20, xx = pix - yy * 20;
            const int gy = ty0 + yy - 2, gx = tx0 + xx - 2;
            float4 val = make_float4(0.f, 0.f, 0.f, 0.f);
            if (gy >= 0 && gy < R_ && gx >= 0 && gx < R_)
                val = *(const float4*)(vb + (size_t)(gy * R_ + gx) * C_ + d4);
            *(float4*)&v_s[pix * 32 + d4] = val;
        }
    }

    const int c  = t & 31, pg = t >> 5;
    float wv[9], wd[25];
    {
        const float* wvp = w_v + (size_t)(h * HD_ + c) * 9;
        const float* wdp = w_dwc + (size_t)c * 25;
        #pragma unroll
        for (int i = 0; i < 9; i++)  wv[i] = wvp[i];
        #pragma unroll
        for (int i = 0; i < 25; i++) wd[i] = wdp[i];
    }
    const float bias = b_v[h * HD_ + c] + b_dwc[c];
    __syncthreads();

    // ---- conv phase: thread = (channel c, 2 tile rows), ring window ----
    float res[32];
    #pragma unroll
    for (int r2 = 0; r2 < 2; r2++) {
        const int ty = pg * 2 + r2;
        float win[5][5];
        #pragma unroll
        for (int j = 0; j < 5; j++)
            #pragma unroll
            for (int i = 0; i < 5; i++)
                win[j][i] = v_s[((ty + i) * 20 + j) * 32 + c];
        #pragma unroll
        for (int tx = 0; tx < 16; tx++) {
            float a = bias;
            #pragma unroll
            for (int j = 0; j < 5; j++) {
                const int slot = (tx + j) % 5;
                #pragma unroll
                for (int i = 0; i < 5; i++)
                    a = fmaf(wd[i * 5 + j], win[slot][i], a);
            }
            #pragma unroll
            for (int j = 1; j < 4; j++) {
                const int slot = (tx + j) % 5;
                #pragma unroll
                for (int i = 1; i < 4; i++)
                    a = fmaf(wv[(i - 1) * 3 + (j - 1)], win[slot][i], a);
            }
            res[r2 * 16 + tx] = a;
            if (tx < 15) {
                const int slot = tx % 5;
                #pragma unroll
                for (int i = 0; i < 5; i++)
                    win[slot][i] = v_s[((ty + i) * 20 + (tx + 5)) * 32 + c];
            }
        }
    }
    __syncthreads();
    #pragma unroll
    for (int r2 = 0; r2 < 2; r2++)
        #pragma unroll
        for (int tx = 0; tx < 16; tx++)
            v_s[((pg * 2 + r2) * 16 + tx) * 33 + c] = res[r2 * 16 + tx];
    __syncthreads();

    // ---- attention phase: thread = pixel; q-feature recomputed on the fly ----
    {
        const int tyy = t >> 4, txx = t & 15;
        const int n   = (ty0 + tyy) * R_ + (tx0 + txx);
        const int tok = b * N_ + n;
        float q[32];
        const float4* qsrc = (const float4*)(qkv + (size_t)tok * C_ + h * HD_);
        #pragma unroll
        for (int i = 0; i < 8; i++) ((float4*)q)[i] = qsrc[i];
        const float qs = qs_arr[tok];
        #pragma unroll
        for (int i = 0; i < 32; i++) {
            const float r = (fmaxf(q[i], 0.f) + 1e-6f) * rsc_s[i];
            q[i] = r * r * r * qs;
        }

        float denom = 1e-6f;
        #pragma unroll
        for (int cc = 0; cc < 32; cc++) denom = fmaf(q[cc], ks_s[cc], denom);
        const float z = 1.f / denom;

        float o[32];
        #pragma unroll
        for (int i = 0; i < 32; i++) o[i] = 0.f;
        #pragma unroll
        for (int cc = 0; cc < 32; cc++) {
            const float qc = q[cc];
            #pragma unroll
            for (int d = 0; d < 32; d++)
                o[d] = fmaf(qc, kv_s[cc * 32 + d], o[d]);
        }
        float4* dst = (float4*)(out + (size_t)tok * C_ + h * HD_);
        #pragma unroll
        for (int i = 0; i < 8; i++) {
            float4 v4;
            v4.x = fmaf(o[i*4+0], z, v_s[t * 33 + i*4+0]);
            v4.y = fmaf(o[i*4+1], z, v_s[t * 33 + i*4+1]);
            v4.z = fmaf(o[i*4+2], z, v_s[t * 33 + i*4+2]);
            v4.w = fmaf(o[i*4+3], z, v_s[t * 33 + i*4+3]);
            dst[i] = v4;
        }
    }
}

// ---------------------------------------------------------------------------
extern "C" void kernel_launch(void* const* d_in, const int* in_sizes, int n_in,
                              void* d_out, int out_size, void* d_ws, size_t ws_size,
                              hipStream_t stream) {
    const float* qkv   = (const float*)d_in[0];
    const float* pos   = (const float*)d_in[1];
    const float* scale = (const float*)d_in[2];
    const float* w_v   = (const float*)d_in[3];
    const float* b_v   = (const float*)d_in[4];
    const float* w_dwc = (const float*)d_in[5];
    const float* b_dwc = (const float*)d_in[6];
    float* out = (float*)d_out;

    float* qs_arr  = (float*)d_ws;                       // 32768 floats
    float* part    = qs_arr + (size_t)B_ * N_;           // 1024*8192 floats
    float* kspart  = part + (size_t)1024 * 8192;         // 1024*256 floats
    float* kv_ws   = kspart + (size_t)1024 * 256;        // 64*1024 floats
    float* ksum_ws = kv_ws + 64 * 1024;                  // 64*32 floats

    kernelNB2<<<dim3(1024), 256, 0, stream>>>(qkv, pos, scale, qs_arr, part, kspart);
    kernelR<<<dim3(256), 256, 0, stream>>>(part, kspart, kv_ws, ksum_ws);
    kernelCD2<<<dim3(16, NH_, B_), 256, 0, stream>>>(qkv, qs_arr, kv_ws, ksum_ws,
                                                     scale, w_v, b_v, w_dwc, b_dwc, out);
}

// Round 3
// 228.871 us; speedup vs baseline: 1.3877x; 1.0074x over previous
//
#include <hip/hip_runtime.h>
#include <math.h>

#define B_  8
#define R_  64
#define C_  256
#define NH_ 8
#define N_  4096
#define HD_ 32
#define LDP 260   // padded LDS row stride (floats): breaks the 1KB bank cycle

__device__ __forceinline__ float softplus_rcp(float s) {
    return 1.f / __logf(1.f + __expf(s));     // 1/softplus, fast intrinsics
}

// ---------------------------------------------------------------------------
// Kernel NB3: fused norms + kv aggregation, 16-lane-per-token reduction.
// R2 lesson: NB2 (~62us vs 21us mem floor) was latency-bound on its 64-lane
// shuffle butterflies: 192 shfl/thread in 6-deep chains gating every barrier.
// Here each token's 256 channels live on 16 lanes (16 ch each), so one wave
// handles 4 tokens/iter and the full-C reduce is a 4-step 16-lane butterfly:
// 32 shfl/thread total (6x fewer), 2x4-deep chains, 4 tokens' chains in
// flight. ksum falls out of phase 2's kr reads for free (dg==0 writes it).
//   phase 1: lane (tk,lr) loads 16 ch of token tk: q,k,pos,v; 16-lane
//     butterfly for qs/ks; kfin=kw^3*ks -> LDS, v -> LDS.
//   phase 2: thread (h=t>>5, cg, dg) accumulates 4x8 sub-tile of head kv
//     + ksum piggyback.
// Epilogue: LDS-staged coalesced partial writes (no atomics; kernelR reduces).
// ---------------------------------------------------------------------------
__global__ __launch_bounds__(256) void kernelNB3(
        const float* __restrict__ qkv, const float* __restrict__ pos,
        const float* __restrict__ scale,
        float* __restrict__ qs_arr, float* __restrict__ part,
        float* __restrict__ kspart) {
    __shared__ float smem[8576];            // 33.5 KB -> 4 blocks/CU by LDS
    float* kf_s  = smem;                    // [16][LDP] (epilogue: stage 8192)
    float* v_s   = smem + 4160;             // [16][LDP]
    float* rsc_s = smem + 8320;             // [256]

    const int t    = threadIdx.x;
    const int wave = t >> 6, lane = t & 63;
    const int tk   = lane >> 4;             // token sub-group within wave, 0..3
    const int lr   = lane & 15;             // lane within token's 16-lane group
    const int blk  = blockIdx.x;
    const int tok0 = blk * 32;

    rsc_s[t] = softplus_rcp(scale[t]);

    const size_t qbase = (size_t)tok0 * C_;
    const size_t koff  = (size_t)B_ * N_ * C_;
    const size_t voff  = (size_t)2 * B_ * N_ * C_;

    const int h  = t >> 5;                  // head 0..7
    const int l  = t & 31;
    const int cg = l & 7;                   // c sub-tile: cg*4 .. cg*4+3
    const int dg = l >> 3;                  // d sub-tile: dg*8 .. dg*8+7

    float acc[4][8];
    #pragma unroll
    for (int ii = 0; ii < 4; ii++)
        #pragma unroll
        for (int jj = 0; jj < 8; jj++) acc[ii][jj] = 0.f;
    float ksp[4] = {0.f, 0.f, 0.f, 0.f};    // ksum piggyback (dg==0 writes)

    __syncthreads();
    float rs[16];
    #pragma unroll
    for (int j = 0; j < 4; j++)
        *(float4*)&rs[j * 4] = *(const float4*)&rsc_s[j * 64 + lr * 4];

    #pragma unroll
    for (int tile = 0; tile < 2; tile++) {
        // ---- phase 1: one token per (wave,tk); 16 lanes cover C=256 ----
        const int row  = wave * 4 + tk;            // 0..15 within tile
        const int nrow = tile * 16 + row;
        const int tok  = tok0 + nrow;
        const size_t off  = qbase + (size_t)nrow * C_;
        const size_t poff = (size_t)(tok & (N_ - 1)) * C_;

        float kc[16];
        float sq2 = 0.f, sq6 = 0.f, sk2 = 0.f, sk6 = 0.f;
        #pragma unroll
        for (int j = 0; j < 4; j++) {
            const int c = j * 64 + lr * 4;
            const float4 q4 = *(const float4*)(qkv + off + c);
            const float4 k4 = *(const float4*)(qkv + koff + off + c);
            const float4 v4 = *(const float4*)(qkv + voff + off + c);
            const float4 p4 = *(const float4*)(pos + poff + c);
            *(float4*)&v_s[row * LDP + c] = v4;
            const float qa[4] = {q4.x, q4.y, q4.z, q4.w};
            const float ka[4] = {k4.x, k4.y, k4.z, k4.w};
            const float pa[4] = {p4.x, p4.y, p4.z, p4.w};
            #pragma unroll
            for (int e = 0; e < 4; e++) {
                const float r  = rs[j * 4 + e];
                const float qv = (fmaxf(qa[e], 0.f) + 1e-6f) * r;
                const float kw = (fmaxf(ka[e] + pa[e], 0.f) + 1e-6f) * r;
                sq2 += qv * qv;  sk2 += kw * kw;
                const float q3 = qv * qv * qv, k3 = kw * kw * kw;
                sq6 += q3 * q3;  sk6 += k3 * k3;
                kc[j * 4 + e] = k3;
            }
        }
        #pragma unroll
        for (int m = 1; m < 16; m <<= 1) {       // 4-step, 16-lane butterfly
            sq2 += __shfl_xor(sq2, m, 64);
            sq6 += __shfl_xor(sq6, m, 64);
            sk2 += __shfl_xor(sk2, m, 64);
            sk6 += __shfl_xor(sk6, m, 64);
        }
        if (lr == 0) qs_arr[tok] = sqrtf(sq2) * rsqrtf(sq6);
        const float ks = sqrtf(sk2) * rsqrtf(sk6);
        #pragma unroll
        for (int j = 0; j < 4; j++) {
            const float4 kf4 = make_float4(kc[j*4+0] * ks, kc[j*4+1] * ks,
                                           kc[j*4+2] * ks, kc[j*4+3] * ks);
            *(float4*)&kf_s[row * LDP + j * 64 + lr * 4] = kf4;
        }
        __syncthreads();
        // ---- phase 2: kv 4x8 outer product + ksum piggyback ----
        {
            const float* kfp = kf_s + h * HD_ + cg * 4;
            const float* vp  = v_s  + h * HD_ + dg * 8;
            #pragma unroll 4
            for (int nl = 0; nl < 16; nl++) {
                const float4 kr = *(const float4*)(kfp + nl * LDP);
                const float4 va = *(const float4*)(vp  + nl * LDP);
                const float4 vb = *(const float4*)(vp  + nl * LDP + 4);
                ksp[0] += kr.x;  ksp[1] += kr.y;
                ksp[2] += kr.z;  ksp[3] += kr.w;
                const float kk[4] = {kr.x, kr.y, kr.z, kr.w};
                const float vv[8] = {va.x, va.y, va.z, va.w,
                                     vb.x, vb.y, vb.z, vb.w};
                #pragma unroll
                for (int ii = 0; ii < 4; ii++)
                    #pragma unroll
                    for (int jj = 0; jj < 8; jj++)
                        acc[ii][jj] = fmaf(kk[ii], vv[jj], acc[ii][jj]);
            }
        }
        __syncthreads();
    }

    // ---- epilogue: stage kv partial in LDS, write coalesced (no atomics) --
    #pragma unroll
    for (int ii = 0; ii < 4; ii++) {
        const float4 a = make_float4(acc[ii][0], acc[ii][1], acc[ii][2], acc[ii][3]);
        const float4 b = make_float4(acc[ii][4], acc[ii][5], acc[ii][6], acc[ii][7]);
        const int base = h * 1024 + (cg * 4 + ii) * 32 + dg * 8;
        *(float4*)&smem[base]     = a;
        *(float4*)&smem[base + 4] = b;
    }
    if (dg == 0)                              // ksum partial, channel h*32+cg*4
        *(float4*)&kspart[(size_t)blk * 256 + h * 32 + cg * 4] =
            make_float4(ksp[0], ksp[1], ksp[2], ksp[3]);
    __syncthreads();
    float* pdst = part + (size_t)blk * 8192;
    #pragma unroll
    for (int i = 0; i < 8; i++)
        *(float4*)&pdst[i * 1024 + t * 4] = *(const float4*)&smem[i * 1024 + t * 4];
}

// ---------------------------------------------------------------------------
// Kernel R: reduce 128 per-block partials -> kv_ws[64][1024], ksum_ws[64][32].
// Grid 256 = 64 bh x 4 quarters; partials are L3-resident (just written).
// Writes kv_ws/ksum_ws destructively (no memset needed).
// ---------------------------------------------------------------------------
__global__ __launch_bounds__(256) void kernelR(
        const float* __restrict__ part, const float* __restrict__ kspart,
        float* __restrict__ kv_ws, float* __restrict__ ksum_ws) {
    const int t  = threadIdx.x;
    const int bh = blockIdx.x >> 2, q = blockIdx.x & 3;
    const int b  = bh >> 3, h = bh & 7;

    const float* p = part + (size_t)(b * 128) * 8192 + h * 1024 + q * 256 + t;
    float s = 0.f;
    #pragma unroll 4
    for (int j = 0; j < 128; j++) s += p[(size_t)j * 8192];
    kv_ws[bh * 1024 + q * 256 + t] = s;

    if (q == 0 && t < 32) {
        const float* kp = kspart + (size_t)(b * 128) * 256 + h * 32 + t;
        float s2 = 0.f;
        #pragma unroll 8
        for (int j = 0; j < 128; j++) s2 += kp[(size_t)j * 256];
        ksum_ws[bh * 32 + t] = s2;
    }
}

// ---------------------------------------------------------------------------
// Kernel CD2: fused attention epilogue + both depthwise convs; out written
// ONCE via plain float4 stores (each lane covers a full 128B line across its
// 8 stores -> L2 write-combines to full-line HBM writes; nontemporal here
// caused 4x write amplification in R4).  [unchanged from verified version]
// ---------------------------------------------------------------------------
__global__ __launch_bounds__(256) void kernelCD2(
        const float* __restrict__ qkv, const float* __restrict__ qs_arr,
        const float* __restrict__ kv_ws, const float* __restrict__ ksum_ws,
        const float* __restrict__ scale,
        const float* __restrict__ w_v,  const float* __restrict__ b_v,
        const float* __restrict__ w_dwc, const float* __restrict__ b_dwc,
        float* __restrict__ out) {
    __shared__ float v_s[20 * 20 * 32];   // 51.2 KB; reused as conv_s (256*33)
    __shared__ float kv_s[1024];
    __shared__ float ks_s[32];
    __shared__ float rsc_s[32];
    const int t    = threadIdx.x;
    const int tile = blockIdx.x;
    const int h    = blockIdx.y;
    const int b    = blockIdx.z;
    const int ty0  = (tile >> 2) * 16, tx0 = (tile & 3) * 16;
    const int bh   = b * NH_ + h;

    ((float4*)kv_s)[t] = ((const float4*)(kv_ws + (size_t)bh * 1024))[t];
    if (t < 32) {
        ks_s[t]  = ksum_ws[bh * HD_ + t];
        rsc_s[t] = softplus_rcp(scale[h * HD_ + t]);
    }

    const float* vb = qkv + (size_t)2 * B_ * N_ * C_ + (size_t)b * N_ * C_ + h * HD_;
    #pragma unroll
    for (int i = 0; i < 13; i++) {
        const int idx = i * 256 + t;
        if (idx < 3200) {
            const int pix = idx >> 3, d4 = (idx & 7) * 4;
            const int yy = pix / 20, xx = pix - yy * 20;
            const int gy = ty0 + yy - 2, gx = tx0 + xx - 2;
            float4 val = make_float4(0.f, 0.f, 0.f, 0.f);
            if (gy >= 0 && gy < R_ && gx >= 0 && gx < R_)
                val = *(const float4*)(vb + (size_t)(gy * R_ + gx) * C_ + d4);
            *(float4*)&v_s[pix * 32 + d4] = val;
        }
    }

    const int c  = t & 31, pg = t >> 5;
    float wv[9], wd[25];
    {
        const float* wvp = w_v + (size_t)(h * HD_ + c) * 9;
        const float* wdp = w_dwc + (size_t)c * 25;
        #pragma unroll
        for (int i = 0; i < 9; i++)  wv[i] = wvp[i];
        #pragma unroll
        for (int i = 0; i < 25; i++) wd[i] = wdp[i];
    }
    const float bias = b_v[h * HD_ + c] + b_dwc[c];
    __syncthreads();

    // ---- conv phase: thread = (channel c, 2 tile rows), ring window ----
    float res[32];
    #pragma unroll
    for (int r2 = 0; r2 < 2; r2++) {
        const int ty = pg * 2 + r2;
        float win[5][5];
        #pragma unroll
        for (int j = 0; j < 5; j++)
            #pragma unroll
            for (int i = 0; i < 5; i++)
                win[j][i] = v_s[((ty + i) * 20 + j) * 32 + c];
        #pragma unroll
        for (int tx = 0; tx < 16; tx++) {
            float a = bias;
            #pragma unroll
            for (int j = 0; j < 5; j++) {
                const int slot = (tx + j) % 5;
                #pragma unroll
                for (int i = 0; i < 5; i++)
                    a = fmaf(wd[i * 5 + j], win[slot][i], a);
            }
            #pragma unroll
            for (int j = 1; j < 4; j++) {
                const int slot = (tx + j) % 5;
                #pragma unroll
                for (int i = 1; i < 4; i++)
                    a = fmaf(wv[(i - 1) * 3 + (j - 1)], win[slot][i], a);
            }
            res[r2 * 16 + tx] = a;
            if (tx < 15) {
                const int slot = tx % 5;
                #pragma unroll
                for (int i = 0; i < 5; i++)
                    win[slot][i] = v_s[((ty + i) * 20 + (tx + 5)) * 32 + c];
            }
        }
    }
    __syncthreads();
    #pragma unroll
    for (int r2 = 0; r2 < 2; r2++)
        #pragma unroll
        for (int tx = 0; tx < 16; tx++)
            v_s[((pg * 2 + r2) * 16 + tx) * 33 + c] = res[r2 * 16 + tx];
    __syncthreads();

    // ---- attention phase: thread = pixel; q-feature recomputed on the fly ----
    {
        const int tyy = t >> 4, txx = t & 15;
        const int n   = (ty0 + tyy) * R_ + (tx0 + txx);
        const int tok = b * N_ + n;
        float q[32];
        const float4* qsrc = (const float4*)(qkv + (size_t)tok * C_ + h * HD_);
        #pragma unroll
        for (int i = 0; i < 8; i++) ((float4*)q)[i] = qsrc[i];
        const float qs = qs_arr[tok];
        #pragma unroll
        for (int i = 0; i < 32; i++) {
            const float r = (fmaxf(q[i], 0.f) + 1e-6f) * rsc_s[i];
            q[i] = r * r * r * qs;
        }

        float denom = 1e-6f;
        #pragma unroll
        for (int cc = 0; cc < 32; cc++) denom = fmaf(q[cc], ks_s[cc], denom);
        const float z = 1.f / denom;

        float o[32];
        #pragma unroll
        for (int i = 0; i < 32; i++) o[i] = 0.f;
        #pragma unroll
        for (int cc = 0; cc < 32; cc++) {
            const float qc = q[cc];
            #pragma unroll
            for (int d = 0; d < 32; d++)
                o[d] = fmaf(qc, kv_s[cc * 32 + d], o[d]);
        }
        float4* dst = (float4*)(out + (size_t)tok * C_ + h * HD_);
        #pragma unroll
        for (int i = 0; i < 8; i++) {
            float4 v4;
            v4.x = fmaf(o[i*4+0], z, v_s[t * 33 + i*4+0]);
            v4.y = fmaf(o[i*4+1], z, v_s[t * 33 + i*4+1]);
            v4.z = fmaf(o[i*4+2], z, v_s[t * 33 + i*4+2]);
            v4.w = fmaf(o[i*4+3], z, v_s[t * 33 + i*4+3]);
            dst[i] = v4;
        }
    }
}

// ---------------------------------------------------------------------------
extern "C" void kernel_launch(void* const* d_in, const int* in_sizes, int n_in,
                              void* d_out, int out_size, void* d_ws, size_t ws_size,
                              hipStream_t stream) {
    const float* qkv   = (const float*)d_in[0];
    const float* pos   = (const float*)d_in[1];
    const float* scale = (const float*)d_in[2];
    const float* w_v   = (const float*)d_in[3];
    const float* b_v   = (const float*)d_in[4];
    const float* w_dwc = (const float*)d_in[5];
    const float* b_dwc = (const float*)d_in[6];
    float* out = (float*)d_out;

    float* qs_arr  = (float*)d_ws;                       // 32768 floats
    float* part    = qs_arr + (size_t)B_ * N_;           // 1024*8192 floats
    float* kspart  = part + (size_t)1024 * 8192;         // 1024*256 floats
    float* kv_ws   = kspart + (size_t)1024 * 256;        // 64*1024 floats
    float* ksum_ws = kv_ws + 64 * 1024;                  // 64*32 floats

    kernelNB3<<<dim3(1024), 256, 0, stream>>>(qkv, pos, scale, qs_arr, part, kspart);
    kernelR<<<dim3(256), 256, 0, stream>>>(part, kspart, kv_ws, ksum_ws);
    kernelCD2<<<dim3(16, NH_, B_), 256, 0, stream>>>(qkv, qs_arr, kv_ws, ksum_ws,
                                                     scale, w_v, b_v, w_dwc, b_dwc, out);
}

// Round 4
// 223.068 us; speedup vs baseline: 1.4238x; 1.0260x over previous
//
#include <hip/hip_runtime.h>
#include <math.h>

#define B_  8
#define R_  64
#define C_  256
#define NH_ 8
#define N_  4096
#define HD_ 32
#define LDP 260   // padded LDS row stride (floats)

__device__ __forceinline__ float softplus_rcp(float s) {
    return 1.f / __logf(1.f + __expf(s));     // 1/softplus, fast intrinsics
}

// ---------------------------------------------------------------------------
// Kernel NB4: fused norms + kv aggregation, SOFTWARE-PIPELINED.
// R3 lesson: NB3 (~53us vs ~20us HBM floor) was duty-cycle-bound: strict
// load-burst -> barrier -> LDS-compute alternation with no prefetch left HBM
// idle during phase 2 (and ALUs idle during phase 1), chip-wide since all
// blocks align. NB4: 512 blocks x 64 tokens, 4 tiles of 16 rows, double-
// buffered LDS (67KB -> 2 blocks/CU), register-staged pipeline:
//   LOAD(0); PROC(0); LOAD(1); bar;
//   t: COMP(t) | PROC(t+1) | LOAD(t+2) | bar
// so tile t+2's global loads are in flight across the barrier while tile t
// computes. One barrier per tile. LDS buffer hazards: PROC(t+1) writes buf
// (t+1)&1 != buf t&1 read by COMP(t); PROC(t+2) (after next barrier) only
// reuses buf t&1 after all waves passed COMP(t) (program order + barrier).
//   phase 1 (PROC): lane (tk,lr) owns 16 ch of token tk; 4-step 16-lane
//     butterfly for qs/ks; kfin=kw^3*ks -> LDS, v -> LDS.
//   phase 2 (COMP): thread (h,cg,dg) accumulates 4x8 sub-tile of head kv;
//     ksum piggybacks on kr reads (dg==0 writes it).
// Epilogue: LDS-staged coalesced partial writes (no atomics; kernelR reduces).
// ---------------------------------------------------------------------------
__global__ __launch_bounds__(256) void kernelNB4(
        const float* __restrict__ qkv, const float* __restrict__ pos,
        const float* __restrict__ scale,
        float* __restrict__ qs_arr, float* __restrict__ part,
        float* __restrict__ kspart) {
    __shared__ float smem[16896];           // 67.6 KB -> 2 blocks/CU
    float* rsc_s = smem + 16640;            // [256]

    const int t    = threadIdx.x;
    const int wave = t >> 6, lane = t & 63;
    const int tk   = lane >> 4;             // token sub-group within wave 0..3
    const int lr   = lane & 15;             // lane within token's 16-lane group
    const int blk  = blockIdx.x;
    const int tok0 = blk * 64;
    const int row  = wave * 4 + tk;         // 0..15: this lane's row in a tile

    rsc_s[t] = softplus_rcp(scale[t]);

    const size_t qbase = (size_t)tok0 * C_;
    const size_t koff  = (size_t)B_ * N_ * C_;
    const size_t voff  = (size_t)2 * B_ * N_ * C_;

    const int h  = t >> 5;                  // head 0..7
    const int l  = t & 31;
    const int cg = l & 7;                   // c sub-tile: cg*4 .. cg*4+3
    const int dg = l >> 3;                  // d sub-tile: dg*8 .. dg*8+7

    float acc[4][8];
    #pragma unroll
    for (int ii = 0; ii < 4; ii++)
        #pragma unroll
        for (int jj = 0; jj < 8; jj++) acc[ii][jj] = 0.f;
    float ksp[4] = {0.f, 0.f, 0.f, 0.f};    // ksum piggyback (dg==0 writes)

    float4 sq[4], sk[4], sv[4], sp[4];      // register staging for one tile

    auto LOAD = [&](int tt) {
        const int    nrow = tt * 16 + row;
        const size_t off  = qbase + (size_t)nrow * C_;
        const size_t poff = (size_t)((tok0 + nrow) & (N_ - 1)) * C_;
        #pragma unroll
        for (int j = 0; j < 4; j++) {
            const int c = j * 64 + lr * 4;
            sq[j] = *(const float4*)(qkv + off + c);
            sk[j] = *(const float4*)(qkv + koff + off + c);
            sv[j] = *(const float4*)(qkv + voff + off + c);
            sp[j] = *(const float4*)(pos + poff + c);
        }
    };

    auto PROC = [&](int tt) {
        float* kf_s = (tt & 1) ? smem + 4160  : smem;
        float* v_s  = (tt & 1) ? smem + 12480 : smem + 8320;
        const int tok = tok0 + tt * 16 + row;
        float kc[16];
        float sq2 = 0.f, sq6 = 0.f, sk2 = 0.f, sk6 = 0.f;
        #pragma unroll
        for (int j = 0; j < 4; j++) {
            const int c = j * 64 + lr * 4;
            *(float4*)&v_s[row * LDP + c] = sv[j];
            const float qa[4] = {sq[j].x, sq[j].y, sq[j].z, sq[j].w};
            const float ka[4] = {sk[j].x, sk[j].y, sk[j].z, sk[j].w};
            const float pa[4] = {sp[j].x, sp[j].y, sp[j].z, sp[j].w};
            #pragma unroll
            for (int e = 0; e < 4; e++) {
                const float r  = rsc_s[c + e];
                const float qv = (fmaxf(qa[e], 0.f) + 1e-6f) * r;
                const float kw = (fmaxf(ka[e] + pa[e], 0.f) + 1e-6f) * r;
                sq2 += qv * qv;  sk2 += kw * kw;
                const float q3 = qv * qv * qv, k3 = kw * kw * kw;
                sq6 += q3 * q3;  sk6 += k3 * k3;
                kc[j * 4 + e] = k3;
            }
        }
        #pragma unroll
        for (int m = 1; m < 16; m <<= 1) {       // 4-step 16-lane butterfly
            sq2 += __shfl_xor(sq2, m, 64);
            sq6 += __shfl_xor(sq6, m, 64);
            sk2 += __shfl_xor(sk2, m, 64);
            sk6 += __shfl_xor(sk6, m, 64);
        }
        if (lr == 0) qs_arr[tok] = sqrtf(sq2) * rsqrtf(sq6);
        const float ks = sqrtf(sk2) * rsqrtf(sk6);
        #pragma unroll
        for (int j = 0; j < 4; j++) {
            const float4 kf4 = make_float4(kc[j*4+0] * ks, kc[j*4+1] * ks,
                                           kc[j*4+2] * ks, kc[j*4+3] * ks);
            *(float4*)&kf_s[row * LDP + j * 64 + lr * 4] = kf4;
        }
    };

    auto COMP = [&](int tt) {
        const float* kf_s = (tt & 1) ? smem + 4160  : smem;
        const float* v_s  = (tt & 1) ? smem + 12480 : smem + 8320;
        const float* kfp = kf_s + h * HD_ + cg * 4;
        const float* vp  = v_s  + h * HD_ + dg * 8;
        #pragma unroll 4
        for (int nl = 0; nl < 16; nl++) {
            const float4 kr = *(const float4*)(kfp + nl * LDP);
            const float4 va = *(const float4*)(vp  + nl * LDP);
            const float4 vb = *(const float4*)(vp  + nl * LDP + 4);
            ksp[0] += kr.x;  ksp[1] += kr.y;
            ksp[2] += kr.z;  ksp[3] += kr.w;
            const float kk[4] = {kr.x, kr.y, kr.z, kr.w};
            const float vv[8] = {va.x, va.y, va.z, va.w,
                                 vb.x, vb.y, vb.z, vb.w};
            #pragma unroll
            for (int ii = 0; ii < 4; ii++)
                #pragma unroll
                for (int jj = 0; jj < 8; jj++)
                    acc[ii][jj] = fmaf(kk[ii], vv[jj], acc[ii][jj]);
        }
    };

    LOAD(0);
    __syncthreads();                 // rsc_s ready (loads already in flight)
    PROC(0);
    LOAD(1);
    __syncthreads();
    #pragma unroll
    for (int tt = 0; tt < 4; tt++) {
        COMP(tt);
        if (tt < 3) PROC(tt + 1);
        if (tt < 2) LOAD(tt + 2);
        if (tt < 3) __syncthreads();
    }
    __syncthreads();                 // COMP(3) done before staging overwrite

    // ---- epilogue: stage kv partial in LDS, write coalesced (no atomics) --
    #pragma unroll
    for (int ii = 0; ii < 4; ii++) {
        const float4 a = make_float4(acc[ii][0], acc[ii][1], acc[ii][2], acc[ii][3]);
        const float4 b = make_float4(acc[ii][4], acc[ii][5], acc[ii][6], acc[ii][7]);
        const int base = h * 1024 + (cg * 4 + ii) * 32 + dg * 8;
        *(float4*)&smem[base]     = a;
        *(float4*)&smem[base + 4] = b;
    }
    if (dg == 0)                              // ksum partial, channel h*32+cg*4
        *(float4*)&kspart[(size_t)blk * 256 + h * 32 + cg * 4] =
            make_float4(ksp[0], ksp[1], ksp[2], ksp[3]);
    __syncthreads();
    float* pdst = part + (size_t)blk * 8192;
    #pragma unroll
    for (int i = 0; i < 8; i++)
        *(float4*)&pdst[i * 1024 + t * 4] = *(const float4*)&smem[i * 1024 + t * 4];
}

// ---------------------------------------------------------------------------
// Kernel R: reduce 64 per-block partials -> kv_ws[64][1024], ksum_ws[64][32].
// Grid 256 = 64 bh x 4 quarters; partials are L3-resident (just written).
// Writes kv_ws/ksum_ws destructively (no memset needed).
// ---------------------------------------------------------------------------
__global__ __launch_bounds__(256) void kernelR(
        const float* __restrict__ part, const float* __restrict__ kspart,
        float* __restrict__ kv_ws, float* __restrict__ ksum_ws) {
    const int t  = threadIdx.x;
    const int bh = blockIdx.x >> 2, q = blockIdx.x & 3;
    const int b  = bh >> 3, h = bh & 7;

    const float* p = part + (size_t)(b * 64) * 8192 + h * 1024 + q * 256 + t;
    float s = 0.f;
    #pragma unroll 4
    for (int j = 0; j < 64; j++) s += p[(size_t)j * 8192];
    kv_ws[bh * 1024 + q * 256 + t] = s;

    if (q == 0 && t < 32) {
        const float* kp = kspart + (size_t)(b * 64) * 256 + h * 32 + t;
        float s2 = 0.f;
        #pragma unroll 8
        for (int j = 0; j < 64; j++) s2 += kp[(size_t)j * 256];
        ksum_ws[bh * 32 + t] = s2;
    }
}

// ---------------------------------------------------------------------------
// Kernel CD2: fused attention epilogue + both depthwise convs; out written
// ONCE via plain float4 stores (each lane covers a full 128B line across its
// 8 stores -> L2 write-combines to full-line HBM writes; nontemporal here
// caused 4x write amplification in R4).  [unchanged from verified version]
// ---------------------------------------------------------------------------
__global__ __launch_bounds__(256) void kernelCD2(
        const float* __restrict__ qkv, const float* __restrict__ qs_arr,
        const float* __restrict__ kv_ws, const float* __restrict__ ksum_ws,
        const float* __restrict__ scale,
        const float* __restrict__ w_v,  const float* __restrict__ b_v,
        const float* __restrict__ w_dwc, const float* __restrict__ b_dwc,
        float* __restrict__ out) {
    __shared__ float v_s[20 * 20 * 32];   // 51.2 KB; reused as conv_s (256*33)
    __shared__ float kv_s[1024];
    __shared__ float ks_s[32];
    __shared__ float rsc_s[32];
    const int t    = threadIdx.x;
    const int tile = blockIdx.x;
    const int h    = blockIdx.y;
    const int b    = blockIdx.z;
    const int ty0  = (tile >> 2) * 16, tx0 = (tile & 3) * 16;
    const int bh   = b * NH_ + h;

    ((float4*)kv_s)[t] = ((const float4*)(kv_ws + (size_t)bh * 1024))[t];
    if (t < 32) {
        ks_s[t]  = ksum_ws[bh * HD_ + t];
        rsc_s[t] = softplus_rcp(scale[h * HD_ + t]);
    }

    const float* vb = qkv + (size_t)2 * B_ * N_ * C_ + (size_t)b * N_ * C_ + h * HD_;
    #pragma unroll
    for (int i = 0; i < 13; i++) {
        const int idx = i * 256 + t;
        if (idx < 3200) {
            const int pix = idx >> 3, d4 = (idx & 7) * 4;
            const int yy = pix / 20, xx = pix - yy * 20;
            const int gy = ty0 + yy - 2, gx = tx0 + xx - 2;
            float4 val = make_float4(0.f, 0.f, 0.f, 0.f);
            if (gy >= 0 && gy < R_ && gx >= 0 && gx < R_)
                val = *(const float4*)(vb + (size_t)(gy * R_ + gx) * C_ + d4);
            *(float4*)&v_s[pix * 32 + d4] = val;
        }
    }

    const int c  = t & 31, pg = t >> 5;
    float wv[9], wd[25];
    {
        const float* wvp = w_v + (size_t)(h * HD_ + c) * 9;
        const float* wdp = w_dwc + (size_t)c * 25;
        #pragma unroll
        for (int i = 0; i < 9; i++)  wv[i] = wvp[i];
        #pragma unroll
        for (int i = 0; i < 25; i++) wd[i] = wdp[i];
    }
    const float bias = b_v[h * HD_ + c] + b_dwc[c];
    __syncthreads();

    // ---- conv phase: thread = (channel c, 2 tile rows), ring window ----
    float res[32];
    #pragma unroll
    for (int r2 = 0; r2 < 2; r2++) {
        const int ty = pg * 2 + r2;
        float win[5][5];
        #pragma unroll
        for (int j = 0; j < 5; j++)
            #pragma unroll
            for (int i = 0; i < 5; i++)
                win[j][i] = v_s[((ty + i) * 20 + j) * 32 + c];
        #pragma unroll
        for (int tx = 0; tx < 16; tx++) {
            float a = bias;
            #pragma unroll
            for (int j = 0; j < 5; j++) {
                const int slot = (tx + j) % 5;
                #pragma unroll
                for (int i = 0; i < 5; i++)
                    a = fmaf(wd[i * 5 + j], win[slot][i], a);
            }
            #pragma unroll
            for (int j = 1; j < 4; j++) {
                const int slot = (tx + j) % 5;
                #pragma unroll
                for (int i = 1; i < 4; i++)
                    a = fmaf(wv[(i - 1) * 3 + (j - 1)], win[slot][i], a);
            }
            res[r2 * 16 + tx] = a;
            if (tx < 15) {
                const int slot = tx % 5;
                #pragma unroll
                for (int i = 0; i < 5; i++)
                    win[slot][i] = v_s[((ty + i) * 20 + (tx + 5)) * 32 + c];
            }
        }
    }
    __syncthreads();
    #pragma unroll
    for (int r2 = 0; r2 < 2; r2++)
        #pragma unroll
        for (int tx = 0; tx < 16; tx++)
            v_s[((pg * 2 + r2) * 16 + tx) * 33 + c] = res[r2 * 16 + tx];
    __syncthreads();

    // ---- attention phase: thread = pixel; q-feature recomputed on the fly ----
    {
        const int tyy = t >> 4, txx = t & 15;
        const int n   = (ty0 + tyy) * R_ + (tx0 + txx);
        const int tok = b * N_ + n;
        float q[32];
        const float4* qsrc = (const float4*)(qkv + (size_t)tok * C_ + h * HD_);
        #pragma unroll
        for (int i = 0; i < 8; i++) ((float4*)q)[i] = qsrc[i];
        const float qs = qs_arr[tok];
        #pragma unroll
        for (int i = 0; i < 32; i++) {
            const float r = (fmaxf(q[i], 0.f) + 1e-6f) * rsc_s[i];
            q[i] = r * r * r * qs;
        }

        float denom = 1e-6f;
        #pragma unroll
        for (int cc = 0; cc < 32; cc++) denom = fmaf(q[cc], ks_s[cc], denom);
        const float z = 1.f / denom;

        float o[32];
        #pragma unroll
        for (int i = 0; i < 32; i++) o[i] = 0.f;
        #pragma unroll
        for (int cc = 0; cc < 32; cc++) {
            const float qc = q[cc];
            #pragma unroll
            for (int d = 0; d < 32; d++)
                o[d] = fmaf(qc, kv_s[cc * 32 + d], o[d]);
        }
        float4* dst = (float4*)(out + (size_t)tok * C_ + h * HD_);
        #pragma unroll
        for (int i = 0; i < 8; i++) {
            float4 v4;
            v4.x = fmaf(o[i*4+0], z, v_s[t * 33 + i*4+0]);
            v4.y = fmaf(o[i*4+1], z, v_s[t * 33 + i*4+1]);
            v4.z = fmaf(o[i*4+2], z, v_s[t * 33 + i*4+2]);
            v4.w = fmaf(o[i*4+3], z, v_s[t * 33 + i*4+3]);
            dst[i] = v4;
        }
    }
}

// ---------------------------------------------------------------------------
extern "C" void kernel_launch(void* const* d_in, const int* in_sizes, int n_in,
                              void* d_out, int out_size, void* d_ws, size_t ws_size,
                              hipStream_t stream) {
    const float* qkv   = (const float*)d_in[0];
    const float* pos   = (const float*)d_in[1];
    const float* scale = (const float*)d_in[2];
    const float* w_v   = (const float*)d_in[3];
    const float* b_v   = (const float*)d_in[4];
    const float* w_dwc = (const float*)d_in[5];
    const float* b_dwc = (const float*)d_in[6];
    float* out = (float*)d_out;

    float* qs_arr  = (float*)d_ws;                       // 32768 floats
    float* part    = qs_arr + (size_t)B_ * N_;           // 512*8192 floats
    float* kspart  = part + (size_t)512 * 8192;          // 512*256 floats
    float* kv_ws   = kspart + (size_t)512 * 256;         // 64*1024 floats
    float* ksum_ws = kv_ws + 64 * 1024;                  // 64*32 floats

    kernelNB4<<<dim3(512), 256, 0, stream>>>(qkv, pos, scale, qs_arr, part, kspart);
    kernelR<<<dim3(256), 256, 0, stream>>>(part, kspart, kv_ws, ksum_ws);
    kernelCD2<<<dim3(16, NH_, B_), 256, 0, stream>>>(qkv, qs_arr, kv_ws, ksum_ws,
                                                     scale, w_v, b_v, w_dwc, b_dwc, out);
}